// Round 4
// baseline (903.451 us; speedup 1.0000x reference)
//
#include <hip/hip_runtime.h>
#include <math.h>

#define D 128

typedef __attribute__((ext_vector_type(8))) short short8;
typedef __attribute__((ext_vector_type(4))) float floatx4;

// ---------------- graph preprocessing ----------------

__global__ __launch_bounds__(256) void k_zero(int* __restrict__ p, int n) {
  int i = blockIdx.x * 256 + threadIdx.x;
  if (i < n) p[i] = 0;
}

__global__ __launch_bounds__(256) void k_hist(const int* __restrict__ dst,
                                              int* __restrict__ counts, int E) {
  int e = blockIdx.x * 256 + threadIdx.x;
  if (e < E) atomicAdd(&counts[dst[e]], 1);
}

__global__ __launch_bounds__(256) void k_scan1(const int* __restrict__ in,
                                               int* __restrict__ out,
                                               int* __restrict__ bsum, int n) {
  __shared__ int sd[256];
  int tid = threadIdx.x;
  int base = blockIdx.x * 1024 + tid * 4;
  int v0 = 0, v1 = 0, v2 = 0, v3 = 0;
  if (base + 3 < n) {
    int4 t = *(const int4*)(in + base);
    v0 = t.x; v1 = t.y; v2 = t.z; v3 = t.w;
  } else {
    if (base     < n) v0 = in[base];
    if (base + 1 < n) v1 = in[base + 1];
    if (base + 2 < n) v2 = in[base + 2];
    if (base + 3 < n) v3 = in[base + 3];
  }
  int s = v0 + v1 + v2 + v3;
  sd[tid] = s;
  __syncthreads();
  for (int off = 1; off < 256; off <<= 1) {
    int t = (tid >= off) ? sd[tid - off] : 0;
    __syncthreads();
    sd[tid] += t;
    __syncthreads();
  }
  int incl = sd[tid];
  int excl = incl - s;
  if (tid == 255) bsum[blockIdx.x] = incl;
  int r = excl;
  if (base     < n) out[base]     = r; r += v0;
  if (base + 1 < n) out[base + 1] = r; r += v1;
  if (base + 2 < n) out[base + 2] = r; r += v2;
  if (base + 3 < n) out[base + 3] = r;
}

__global__ __launch_bounds__(256) void k_scan2(int* __restrict__ bsum, int nb) {
  __shared__ int sd[256];
  int tid = threadIdx.x;
  int v = (tid < nb) ? bsum[tid] : 0;
  sd[tid] = v;
  __syncthreads();
  for (int off = 1; off < 256; off <<= 1) {
    int t = (tid >= off) ? sd[tid - off] : 0;
    __syncthreads();
    sd[tid] += t;
    __syncthreads();
  }
  int excl = sd[tid] - v;
  if (tid < nb) bsum[tid] = excl;
}

__global__ __launch_bounds__(256) void k_finish(int* __restrict__ rowptr,
                                                int* __restrict__ cursor,
                                                float* __restrict__ dis,
                                                const int* __restrict__ counts,
                                                const int* __restrict__ bsum, int n) {
  int i = blockIdx.x * 256 + threadIdx.x;
  if (i < n) {
    int r = rowptr[i] + bsum[i >> 10];
    rowptr[i] = r;
    cursor[i] = r;
    dis[i] = rsqrtf((float)(counts[i] + 1));
  }
}

// packed CSR payload: one 8B scatter per edge (src, norm-bits)
__global__ __launch_bounds__(256) void k_fill(const int* __restrict__ src,
                                              const int* __restrict__ dst,
                                              int* __restrict__ cursor,
                                              const float* __restrict__ dis,
                                              int2* __restrict__ cpack, int E) {
  int e = blockIdx.x * 256 + threadIdx.x;
  if (e < E) {
    int s = src[e], d = dst[e];
    int pos = atomicAdd(&cursor[d], 1);
    float nw = dis[s] * dis[d];
    cpack[pos] = make_int2(s, __float_as_int(nw));
  }
}

// ---------------- weight pre-split (once per call) ----------------
// 128x128 weights -> image [c][k] (c,k in 0..127): hi/lo bf16 of W[k][c].
// Wm2 (128x40, padded 48 cols) -> image [c][k]: hi/lo of Wm2[k][c].

__device__ __forceinline__ short f2bf(float v) {
  unsigned u = __float_as_uint(v);
  unsigned r = (u + 0x7FFFu + ((u >> 16) & 1u)) >> 16;
  return (short)r;
}
__device__ __forceinline__ float bf2f(short s) {
  return __uint_as_float(((unsigned)(unsigned short)s) << 16);
}

__global__ __launch_bounds__(256) void k_prep(const float* __restrict__ W1,
                                              const float* __restrict__ W2,
                                              const float* __restrict__ W3,
                                              const float* __restrict__ Wm1,
                                              const float* __restrict__ Wm2,
                                              short* __restrict__ wsplit,
                                              short* __restrict__ w2hi,
                                              short* __restrict__ w2lo) {
  int idx = blockIdx.x * 256 + threadIdx.x;
  if (idx < 65536) {
    int w = idx >> 14;            // which weight
    int rem = idx & 16383;        // c*128 + k
    int c = rem >> 7, k = rem & 127;
    const float* Ws = (w == 0) ? W1 : (w == 1) ? W2 : (w == 2) ? W3 : Wm1;
    float v = Ws[k * D + c];
    short hi = f2bf(v);
    short lo = f2bf(v - bf2f(hi));
    wsplit[(size_t)w * 32768 + rem] = hi;
    wsplit[(size_t)w * 32768 + 16384 + rem] = lo;
  } else if (idx < 65536 + 6144) {
    int i2 = idx - 65536;         // c*128 + k, c in 0..47
    int c = i2 >> 7, k = i2 & 127;
    float v = (c < 40) ? Wm2[k * 40 + c] : 0.f;
    short hi = f2bf(v);
    short lo = f2bf(v - bf2f(hi));
    w2hi[i2] = hi;
    w2lo[i2] = lo;
  }
}

// ---------------- bf16-split MFMA GEMM (no LDS): Y = X @ W (+bias, +ELU) -------
// B fragments straight from global pre-split images (L2-hot, 128KB).
// 3-product reconstruction: hi*hi + lo*hi + hi*lo (lo*lo ~2^-18 rel, dropped).
// Block 256 = 4 waves; wave owns 32 rows (2 row-tiles of 16); block = 128 rows.

__device__ __forceinline__ float elu1(float x) {
  return x > 0.f ? x : (expf(x) - 1.f);
}

__global__ __launch_bounds__(256, 3) void k_gemm(const float* __restrict__ X,
                                                 const short* __restrict__ Whi,
                                                 const short* __restrict__ Wlo,
                                                 const float* __restrict__ bias,
                                                 float* __restrict__ Y, int n, int act) {
  int tid = threadIdx.x;
  int wave = tid >> 6, lane = tid & 63;
  int q = lane >> 4, r = lane & 15;

  long rowbase = (long)blockIdx.x * 128 + wave * 32;
  long row0 = rowbase + r;
  long row1 = rowbase + 16 + r;
  long rc0 = row0 < n ? row0 : (n - 1);
  long rc1 = row1 < n ? row1 : (n - 1);
  const floatx4* x0 = (const floatx4*)(X + rc0 * D);
  const floatx4* x1 = (const floatx4*)(X + rc1 * D);

  floatx4 acc[2][8];
#pragma unroll
  for (int rt = 0; rt < 2; rt++)
#pragma unroll
    for (int ct = 0; ct < 8; ct++) acc[rt][ct] = (floatx4){0.f, 0.f, 0.f, 0.f};

#pragma unroll
  for (int ks = 0; ks < 4; ks++) {
    int xi = ks * 8 + q * 2;
    floatx4 a0 = x0[xi], a0b = x0[xi + 1];
    floatx4 a1 = x1[xi], a1b = x1[xi + 1];
    short8 ahi0, alo0, ahi1, alo1;
#pragma unroll
    for (int j = 0; j < 4; j++) {
      float v = a0[j];  short hi = f2bf(v);
      ahi0[j] = hi; alo0[j] = f2bf(v - bf2f(hi));
      v = a0b[j]; hi = f2bf(v);
      ahi0[4 + j] = hi; alo0[4 + j] = f2bf(v - bf2f(hi));
      v = a1[j];  hi = f2bf(v);
      ahi1[j] = hi; alo1[j] = f2bf(v - bf2f(hi));
      v = a1b[j]; hi = f2bf(v);
      ahi1[4 + j] = hi; alo1[4 + j] = f2bf(v - bf2f(hi));
    }
    const short* bph = Whi + ks * 32 + q * 8;
    const short* bpl = Wlo + ks * 32 + q * 8;
#pragma unroll
    for (int ct = 0; ct < 8; ct++) {
      int c = ct * 16 + r;
      short8 bh = *(const short8*)&bph[c * D];
      short8 bl = *(const short8*)&bpl[c * D];
      acc[0][ct] = __builtin_amdgcn_mfma_f32_16x16x32_bf16(ahi0, bh, acc[0][ct], 0, 0, 0);
      acc[0][ct] = __builtin_amdgcn_mfma_f32_16x16x32_bf16(alo0, bh, acc[0][ct], 0, 0, 0);
      acc[0][ct] = __builtin_amdgcn_mfma_f32_16x16x32_bf16(ahi0, bl, acc[0][ct], 0, 0, 0);
      acc[1][ct] = __builtin_amdgcn_mfma_f32_16x16x32_bf16(ahi1, bh, acc[1][ct], 0, 0, 0);
      acc[1][ct] = __builtin_amdgcn_mfma_f32_16x16x32_bf16(alo1, bh, acc[1][ct], 0, 0, 0);
      acc[1][ct] = __builtin_amdgcn_mfma_f32_16x16x32_bf16(ahi1, bl, acc[1][ct], 0, 0, 0);
    }
  }

  // epilogue: C/D layout col = lane&15, row = q*4 + reg
#pragma unroll
  for (int rt = 0; rt < 2; rt++) {
#pragma unroll
    for (int i = 0; i < 4; i++) {
      long row = rowbase + rt * 16 + q * 4 + i;
      if (row < n) {
#pragma unroll
        for (int ct = 0; ct < 8; ct++) {
          int col = ct * 16 + r;
          float v = acc[rt][ct][i];
          if (bias) v += bias[col];
          if (act == 1) v = elu1(v);
          Y[row * D + col] = v;
        }
      }
    }
  }
}

// ---------------- aggregation ----------------
// Y[d] = relu(sum_{e: dst=d} T[src]*norm + T[d]*dis[d]^2 + b)
// one wave per node; float4 lanes (32 lanes/row); 2 edges per load instr;
// unroll 8 -> 16 edges (one avg node) in flight per batch.

__global__ __launch_bounds__(256) void k_agg(const float* __restrict__ T,
                                             const int* __restrict__ rowptr,
                                             const int* __restrict__ counts,
                                             const int2* __restrict__ cpack,
                                             const float* __restrict__ dis,
                                             const float* __restrict__ bias,
                                             float* __restrict__ Y, int n) {
  int node = blockIdx.x * 4 + (threadIdx.x >> 6);
  if (node >= n) return;
  int lane = threadIdx.x & 63;
  int half = lane >> 5;     // 0: even edges, 1: odd edges
  int fc = lane & 31;       // float4 column
  const float4* T4 = (const float4*)T;

  int s = rowptr[node];
  int e = s + counts[node];
  float dv = dis[node];
  float4 t = T4[(size_t)node * 32 + fc];
  float sw = half ? 0.f : dv * dv;   // self-loop only in half 0
  float ax = t.x * sw, ay = t.y * sw, az = t.z * sw, aw = t.w * sw;
  float bx = 0.f, by = 0.f, bz = 0.f, bw = 0.f;

  int j = s;
  for (; j + 15 < e; j += 16) {
    int2 m0 = cpack[j +  0 + half], m1 = cpack[j +  2 + half];
    int2 m2 = cpack[j +  4 + half], m3 = cpack[j +  6 + half];
    int2 m4 = cpack[j +  8 + half], m5 = cpack[j + 10 + half];
    int2 m6 = cpack[j + 12 + half], m7 = cpack[j + 14 + half];
    float4 v0 = T4[(size_t)m0.x * 32 + fc];
    float4 v1 = T4[(size_t)m1.x * 32 + fc];
    float4 v2 = T4[(size_t)m2.x * 32 + fc];
    float4 v3 = T4[(size_t)m3.x * 32 + fc];
    float4 v4 = T4[(size_t)m4.x * 32 + fc];
    float4 v5 = T4[(size_t)m5.x * 32 + fc];
    float4 v6 = T4[(size_t)m6.x * 32 + fc];
    float4 v7 = T4[(size_t)m7.x * 32 + fc];
    float n0 = __int_as_float(m0.y), n1 = __int_as_float(m1.y);
    float n2 = __int_as_float(m2.y), n3 = __int_as_float(m3.y);
    float n4 = __int_as_float(m4.y), n5 = __int_as_float(m5.y);
    float n6 = __int_as_float(m6.y), n7 = __int_as_float(m7.y);
    ax += v0.x * n0; ay += v0.y * n0; az += v0.z * n0; aw += v0.w * n0;
    bx += v1.x * n1; by += v1.y * n1; bz += v1.z * n1; bw += v1.w * n1;
    ax += v2.x * n2; ay += v2.y * n2; az += v2.z * n2; aw += v2.w * n2;
    bx += v3.x * n3; by += v3.y * n3; bz += v3.z * n3; bw += v3.w * n3;
    ax += v4.x * n4; ay += v4.y * n4; az += v4.z * n4; aw += v4.w * n4;
    bx += v5.x * n5; by += v5.y * n5; bz += v5.z * n5; bw += v5.w * n5;
    ax += v6.x * n6; ay += v6.y * n6; az += v6.z * n6; aw += v6.w * n6;
    bx += v7.x * n7; by += v7.y * n7; bz += v7.z * n7; bw += v7.w * n7;
  }
  for (; j < e; j += 2) {
    int idx = j + half;
    int2 mm;
    if (idx < e) mm = cpack[idx];
    else { mm.x = 0; mm.y = 0; }          // norm 0 -> contributes 0
    float4 v = T4[(size_t)mm.x * 32 + fc];
    float nw = __int_as_float(mm.y);
    ax += v.x * nw; ay += v.y * nw; az += v.z * nw; aw += v.w * nw;
  }

  ax += bx; ay += by; az += bz; aw += bw;
  float ox = ax + __shfl_xor(ax, 32);
  float oy = ay + __shfl_xor(ay, 32);
  float oz = az + __shfl_xor(az, 32);
  float ow = aw + __shfl_xor(aw, 32);
  if (half == 0) {
    const float4* B4 = (const float4*)bias;
    float4 bb = B4[fc];
    float4 o;
    o.x = fmaxf(ox + bb.x, 0.f);
    o.y = fmaxf(oy + bb.y, 0.f);
    o.z = fmaxf(oz + bb.z, 0.f);
    o.w = fmaxf(ow + bb.w, 0.f);
    *(float4*)&Y[(size_t)node * D + fc * 4] = o;
  }
}

// ---------------- MLP head: MFMA GEMM (128->48 cols, 40 valid) + fused softmax ----

__global__ __launch_bounds__(256) void k_head(const float* __restrict__ M,
                                              const short* __restrict__ Whi,
                                              const short* __restrict__ Wlo,
                                              const float* __restrict__ b,
                                              float* __restrict__ logits,
                                              float* __restrict__ probs, int n) {
  int tid = threadIdx.x;
  int wave = tid >> 6, lane = tid & 63;
  int q = lane >> 4, r = lane & 15;

  long rowbase = (long)blockIdx.x * 128 + wave * 32;
  long row0 = rowbase + r;
  long row1 = rowbase + 16 + r;
  long rc0 = row0 < n ? row0 : (n - 1);
  long rc1 = row1 < n ? row1 : (n - 1);
  const floatx4* x0 = (const floatx4*)(M + rc0 * D);
  const floatx4* x1 = (const floatx4*)(M + rc1 * D);

  floatx4 acc[2][3];
#pragma unroll
  for (int rt = 0; rt < 2; rt++)
#pragma unroll
    for (int ct = 0; ct < 3; ct++) acc[rt][ct] = (floatx4){0.f, 0.f, 0.f, 0.f};

#pragma unroll
  for (int ks = 0; ks < 4; ks++) {
    int xi = ks * 8 + q * 2;
    floatx4 a0 = x0[xi], a0b = x0[xi + 1];
    floatx4 a1 = x1[xi], a1b = x1[xi + 1];
    short8 ahi0, alo0, ahi1, alo1;
#pragma unroll
    for (int j = 0; j < 4; j++) {
      float v = a0[j];  short hi = f2bf(v);
      ahi0[j] = hi; alo0[j] = f2bf(v - bf2f(hi));
      v = a0b[j]; hi = f2bf(v);
      ahi0[4 + j] = hi; alo0[4 + j] = f2bf(v - bf2f(hi));
      v = a1[j];  hi = f2bf(v);
      ahi1[j] = hi; alo1[j] = f2bf(v - bf2f(hi));
      v = a1b[j]; hi = f2bf(v);
      ahi1[4 + j] = hi; alo1[4 + j] = f2bf(v - bf2f(hi));
    }
#pragma unroll
    for (int ct = 0; ct < 3; ct++) {
      int c = ct * 16 + r;
      short8 bh = *(const short8*)&Whi[c * D + ks * 32 + q * 8];
      short8 bl = *(const short8*)&Wlo[c * D + ks * 32 + q * 8];
      acc[0][ct] = __builtin_amdgcn_mfma_f32_16x16x32_bf16(ahi0, bh, acc[0][ct], 0, 0, 0);
      acc[0][ct] = __builtin_amdgcn_mfma_f32_16x16x32_bf16(alo0, bh, acc[0][ct], 0, 0, 0);
      acc[0][ct] = __builtin_amdgcn_mfma_f32_16x16x32_bf16(ahi0, bl, acc[0][ct], 0, 0, 0);
      acc[1][ct] = __builtin_amdgcn_mfma_f32_16x16x32_bf16(ahi1, bh, acc[1][ct], 0, 0, 0);
      acc[1][ct] = __builtin_amdgcn_mfma_f32_16x16x32_bf16(alo1, bh, acc[1][ct], 0, 0, 0);
      acc[1][ct] = __builtin_amdgcn_mfma_f32_16x16x32_bf16(ahi1, bl, acc[1][ct], 0, 0, 0);
    }
  }

  float bb0 = b[r];
  float bb1 = b[16 + r];
  float bb2 = (r < 8) ? b[32 + r] : 0.f;

#pragma unroll
  for (int rt = 0; rt < 2; rt++) {
#pragma unroll
    for (int i = 0; i < 4; i++) {
      long row = rowbase + rt * 16 + q * 4 + i;
      float v0 = acc[rt][0][i] + bb0;
      float v1 = acc[rt][1][i] + bb1;
      float v2 = (r < 8) ? (acc[rt][2][i] + bb2) : -INFINITY;
      float mx = fmaxf(fmaxf(v0, v1), v2);
      mx = fmaxf(mx, __shfl_xor(mx, 1));
      mx = fmaxf(mx, __shfl_xor(mx, 2));
      mx = fmaxf(mx, __shfl_xor(mx, 4));
      mx = fmaxf(mx, __shfl_xor(mx, 8));
      float e0 = expf(v0 - mx);
      float e1 = expf(v1 - mx);
      float e2 = (r < 8) ? expf(v2 - mx) : 0.f;
      float sm = e0 + e1 + e2;
      sm += __shfl_xor(sm, 1);
      sm += __shfl_xor(sm, 2);
      sm += __shfl_xor(sm, 4);
      sm += __shfl_xor(sm, 8);
      float inv = 1.f / sm;
      if (row < n) {
        float* lp = logits + row * 40;
        float* pp = probs + row * 40;
        lp[r] = v0;      pp[r] = e0 * inv;
        lp[16 + r] = v1; pp[16 + r] = e1 * inv;
        if (r < 8) { lp[32 + r] = v2; pp[32 + r] = e2 * inv; }
      }
    }
  }
}

// ---------------- launcher ----------------

extern "C" void kernel_launch(void* const* d_in, const int* in_sizes, int n_in,
                              void* d_out, int out_size, void* d_ws, size_t ws_size,
                              hipStream_t stream) {
  const float* x   = (const float*)d_in[0];
  const int*   ei  = (const int*)d_in[1];
  const float* W1  = (const float*)d_in[2];
  const float* b1  = (const float*)d_in[3];
  const float* W2  = (const float*)d_in[4];
  const float* b2  = (const float*)d_in[5];
  const float* W3  = (const float*)d_in[6];
  const float* b3  = (const float*)d_in[7];
  const float* Wm1 = (const float*)d_in[8];
  const float* bm1 = (const float*)d_in[9];
  const float* Wm2 = (const float*)d_in[10];
  const float* bm2 = (const float*)d_in[11];

  int N = in_sizes[0] / D;
  int E = in_sizes[1] / 2;
  const int* srcp = ei;
  const int* dstp = ei + E;

  char* w = (char*)d_ws;
  auto alloc = [&](size_t bytes) -> char* {
    char* p = w;
    w += (bytes + 255) & ~(size_t)255;
    return p;
  };
  int*   counts = (int*)alloc((size_t)N * 4);
  int*   rowptr = (int*)alloc((size_t)N * 4);
  int*   cursor = (int*)alloc((size_t)N * 4);
  float* dis    = (float*)alloc((size_t)N * 4);
  int*   bsum   = (int*)alloc(1024);
  short* wsplit = (short*)alloc(4 * 32768 * 2);   // 4 weights x (hi+lo 16384 shorts)
  short* w2hi   = (short*)alloc(6144 * 2);
  short* w2lo   = (short*)alloc(6144 * 2);
  int2*  cpack  = (int2*)alloc((size_t)E * 8);
  float* tmp    = (float*)alloc((size_t)N * D * 4);
  float* hbuf   = (float*)alloc((size_t)N * D * 4);

  float* logits = (float*)d_out;
  float* probs  = logits + (size_t)N * 40;
  float* emb    = probs + (size_t)N * 40;

  // weight pre-split
  k_prep<<<(65536 + 6144 + 255) / 256, 256, 0, stream>>>(W1, W2, W3, Wm1, Wm2,
                                                         wsplit, w2hi, w2lo);
  // CSR build
  k_zero<<<(N + 255) / 256, 256, 0, stream>>>(counts, N);
  k_hist<<<(E + 255) / 256, 256, 0, stream>>>(dstp, counts, E);
  int nb = (N + 1023) / 1024;
  k_scan1<<<nb, 256, 0, stream>>>(counts, rowptr, bsum, N);
  k_scan2<<<1, 256, 0, stream>>>(bsum, nb);
  k_finish<<<(N + 255) / 256, 256, 0, stream>>>(rowptr, cursor, dis, counts, bsum, N);
  k_fill<<<(E + 255) / 256, 256, 0, stream>>>(srcp, dstp, cursor, dis, cpack, E);

  int gblocks = (N + 127) / 128;
  int ablocks = (N + 3) / 4;
  const short* Whi1 = wsplit;
  const short* Wlo1 = wsplit + 16384;
  const short* Whi2 = wsplit + 32768;
  const short* Wlo2 = wsplit + 32768 + 16384;
  const short* Whi3 = wsplit + 2 * 32768;
  const short* Wlo3 = wsplit + 2 * 32768 + 16384;
  const short* Whm1 = wsplit + 3 * 32768;
  const short* Wlm1 = wsplit + 3 * 32768 + 16384;

  // layer 1
  k_gemm<<<gblocks, 256, 0, stream>>>(x, Whi1, Wlo1, nullptr, tmp, N, 0);
  k_agg<<<ablocks, 256, 0, stream>>>(tmp, rowptr, counts, cpack, dis, b1, hbuf, N);
  // layer 2
  k_gemm<<<gblocks, 256, 0, stream>>>(hbuf, Whi2, Wlo2, nullptr, tmp, N, 0);
  k_agg<<<ablocks, 256, 0, stream>>>(tmp, rowptr, counts, cpack, dis, b2, hbuf, N);
  // layer 3 -> emb
  k_gemm<<<gblocks, 256, 0, stream>>>(hbuf, Whi3, Wlo3, nullptr, tmp, N, 0);
  k_agg<<<ablocks, 256, 0, stream>>>(tmp, rowptr, counts, cpack, dis, b3, emb, N);
  // MLP head
  k_gemm<<<gblocks, 256, 0, stream>>>(emb, Whm1, Wlm1, bm1, tmp, N, 1);
  k_head<<<gblocks, 256, 0, stream>>>(tmp, w2hi, w2lo, bm2, logits, probs, N);
}

// Round 5
// 838.625 us; speedup vs baseline: 1.0773x; 1.0773x over previous
//
#include <hip/hip_runtime.h>
#include <math.h>

#define D 128

typedef __attribute__((ext_vector_type(8))) short short8;
typedef __attribute__((ext_vector_type(4))) float floatx4;

// ---------------- graph preprocessing ----------------

__global__ __launch_bounds__(256) void k_zero(int* __restrict__ p, int n) {
  int i = blockIdx.x * 256 + threadIdx.x;
  if (i < n) p[i] = 0;
}

__global__ __launch_bounds__(256) void k_hist(const int* __restrict__ dst,
                                              int* __restrict__ counts, int E) {
  int e = blockIdx.x * 256 + threadIdx.x;
  if (e < E) atomicAdd(&counts[dst[e]], 1);
}

__global__ __launch_bounds__(256) void k_scan1(const int* __restrict__ in,
                                               int* __restrict__ out,
                                               int* __restrict__ bsum, int n) {
  __shared__ int sd[256];
  int tid = threadIdx.x;
  int base = blockIdx.x * 1024 + tid * 4;
  int v0 = 0, v1 = 0, v2 = 0, v3 = 0;
  if (base + 3 < n) {
    int4 t = *(const int4*)(in + base);
    v0 = t.x; v1 = t.y; v2 = t.z; v3 = t.w;
  } else {
    if (base     < n) v0 = in[base];
    if (base + 1 < n) v1 = in[base + 1];
    if (base + 2 < n) v2 = in[base + 2];
    if (base + 3 < n) v3 = in[base + 3];
  }
  int s = v0 + v1 + v2 + v3;
  sd[tid] = s;
  __syncthreads();
  for (int off = 1; off < 256; off <<= 1) {
    int t = (tid >= off) ? sd[tid - off] : 0;
    __syncthreads();
    sd[tid] += t;
    __syncthreads();
  }
  int incl = sd[tid];
  int excl = incl - s;
  if (tid == 255) bsum[blockIdx.x] = incl;
  int r = excl;
  if (base     < n) out[base]     = r; r += v0;
  if (base + 1 < n) out[base + 1] = r; r += v1;
  if (base + 2 < n) out[base + 2] = r; r += v2;
  if (base + 3 < n) out[base + 3] = r;
}

__global__ __launch_bounds__(256) void k_scan2(int* __restrict__ bsum, int nb) {
  __shared__ int sd[256];
  int tid = threadIdx.x;
  int v = (tid < nb) ? bsum[tid] : 0;
  sd[tid] = v;
  __syncthreads();
  for (int off = 1; off < 256; off <<= 1) {
    int t = (tid >= off) ? sd[tid - off] : 0;
    __syncthreads();
    sd[tid] += t;
    __syncthreads();
  }
  int excl = sd[tid] - v;
  if (tid < nb) bsum[tid] = excl;
}

__global__ __launch_bounds__(256) void k_finish(int* __restrict__ rowptr,
                                                int* __restrict__ cursor,
                                                float* __restrict__ dis,
                                                const int* __restrict__ counts,
                                                const int* __restrict__ bsum, int n) {
  int i = blockIdx.x * 256 + threadIdx.x;
  if (i < n) {
    int r = rowptr[i] + bsum[i >> 10];
    rowptr[i] = r;
    cursor[i] = r;
    dis[i] = rsqrtf((float)(counts[i] + 1));
  }
}

// packed CSR payload: one 8B scatter per edge (src, norm-bits)
__global__ __launch_bounds__(256) void k_fill(const int* __restrict__ src,
                                              const int* __restrict__ dst,
                                              int* __restrict__ cursor,
                                              const float* __restrict__ dis,
                                              int2* __restrict__ cpack, int E) {
  int e = blockIdx.x * 256 + threadIdx.x;
  if (e < E) {
    int s = src[e], d = dst[e];
    int pos = atomicAdd(&cursor[d], 1);
    float nw = dis[s] * dis[d];
    cpack[pos] = make_int2(s, __float_as_int(nw));
  }
}

// ---------------- weight pre-split (once per call) ----------------
// 128x128 weights -> image [c][k] (c,k in 0..127): hi/lo bf16 of W[k][c].
// Wm2 (128x40, padded 48 cols) -> image [c][k]: hi/lo of Wm2[k][c].

__device__ __forceinline__ short f2bf(float v) {
  unsigned u = __float_as_uint(v);
  unsigned r = (u + 0x7FFFu + ((u >> 16) & 1u)) >> 16;
  return (short)r;
}
__device__ __forceinline__ float bf2f(short s) {
  return __uint_as_float(((unsigned)(unsigned short)s) << 16);
}

__global__ __launch_bounds__(256) void k_prep(const float* __restrict__ W1,
                                              const float* __restrict__ W2,
                                              const float* __restrict__ W3,
                                              const float* __restrict__ Wm1,
                                              const float* __restrict__ Wm2,
                                              short* __restrict__ wsplit,
                                              short* __restrict__ w2hi,
                                              short* __restrict__ w2lo) {
  int idx = blockIdx.x * 256 + threadIdx.x;
  if (idx < 65536) {
    int w = idx >> 14;            // which weight
    int rem = idx & 16383;        // c*128 + k
    int c = rem >> 7, k = rem & 127;
    const float* Ws = (w == 0) ? W1 : (w == 1) ? W2 : (w == 2) ? W3 : Wm1;
    float v = Ws[k * D + c];
    short hi = f2bf(v);
    short lo = f2bf(v - bf2f(hi));
    wsplit[(size_t)w * 32768 + rem] = hi;
    wsplit[(size_t)w * 32768 + 16384 + rem] = lo;
  } else if (idx < 65536 + 6144) {
    int i2 = idx - 65536;         // c*128 + k, c in 0..47
    int c = i2 >> 7, k = i2 & 127;
    float v = (c < 40) ? Wm2[k * 40 + c] : 0.f;
    short hi = f2bf(v);
    short lo = f2bf(v - bf2f(hi));
    w2hi[i2] = hi;
    w2lo[i2] = lo;
  }
}

// ---------------- bf16-split MFMA GEMM: Y = X @ W (+bias, +ELU) ----------------
// B staged in LDS (padded stride 72) per half-K; A either fp32 (amode=0,
// in-kernel split) or pre-split planes (amode=1: row*256, [0:128) hi [128:256) lo).
// 3-product reconstruction: hi*hi + lo*hi + hi*lo.
// omode=0: fp32 out; omode=1: split out (row*256 hi/lo planes).

__device__ __forceinline__ float elu1(float x) {
  return x > 0.f ? x : (expf(x) - 1.f);
}

__global__ __launch_bounds__(256, 2) void k_gemm(const float* __restrict__ Xf,
                                                 const short* __restrict__ Xs,
                                                 const short* __restrict__ Whi,
                                                 const short* __restrict__ Wlo,
                                                 const float* __restrict__ bias,
                                                 float* __restrict__ Yf,
                                                 short* __restrict__ Ys,
                                                 int n, int act, int amode, int omode) {
  __shared__ short wthi[128 * 72];  // [c][kk-half], padded stride 72
  __shared__ short wtlo[128 * 72];

  int tid = threadIdx.x;
  int wave = tid >> 6, lane = tid & 63;
  int q = lane >> 4, r = lane & 15;

  long rowbase = (long)blockIdx.x * 128 + wave * 32;
  long row0 = rowbase + r;
  long row1 = rowbase + 16 + r;
  long rc0 = row0 < n ? row0 : (n - 1);
  long rc1 = row1 < n ? row1 : (n - 1);

  floatx4 acc[2][8];
#pragma unroll
  for (int rt = 0; rt < 2; rt++)
#pragma unroll
    for (int ct = 0; ct < 8; ct++) acc[rt][ct] = (floatx4){0.f, 0.f, 0.f, 0.f};

  for (int h = 0; h < 2; h++) {
    __syncthreads();
    // stage half-K of pre-split W images into padded LDS (plain short8 copies)
#pragma unroll
    for (int i = 0; i < 4; i++) {
      int cs = i * 256 + tid;           // 1024 chunks of 8 shorts
      int c = cs >> 3, o = (cs & 7) * 8;
      *(short8*)&wthi[c * 72 + o] = *(const short8*)&Whi[c * D + h * 64 + o];
      *(short8*)&wtlo[c * 72 + o] = *(const short8*)&Wlo[c * D + h * 64 + o];
    }
    __syncthreads();

#pragma unroll
    for (int ks2 = 0; ks2 < 2; ks2++) {
      int ksg = h * 2 + ks2;            // global k-step 0..3
      int kk0 = ks2 * 32;
      short8 ahi0, alo0, ahi1, alo1;
      if (amode == 1) {
        const short* p0 = Xs + rc0 * 256 + ksg * 32 + q * 8;
        const short* p1 = Xs + rc1 * 256 + ksg * 32 + q * 8;
        ahi0 = *(const short8*)p0;
        alo0 = *(const short8*)(p0 + 128);
        ahi1 = *(const short8*)p1;
        alo1 = *(const short8*)(p1 + 128);
      } else {
        const floatx4* x0 = (const floatx4*)(Xf + rc0 * D);
        const floatx4* x1 = (const floatx4*)(Xf + rc1 * D);
        int xi = ksg * 8 + q * 2;
        floatx4 a0 = x0[xi], a0b = x0[xi + 1];
        floatx4 a1 = x1[xi], a1b = x1[xi + 1];
#pragma unroll
        for (int j = 0; j < 4; j++) {
          float v = a0[j];  short hi = f2bf(v);
          ahi0[j] = hi; alo0[j] = f2bf(v - bf2f(hi));
          v = a0b[j]; hi = f2bf(v);
          ahi0[4 + j] = hi; alo0[4 + j] = f2bf(v - bf2f(hi));
          v = a1[j];  hi = f2bf(v);
          ahi1[j] = hi; alo1[j] = f2bf(v - bf2f(hi));
          v = a1b[j]; hi = f2bf(v);
          ahi1[4 + j] = hi; alo1[4 + j] = f2bf(v - bf2f(hi));
        }
      }
#pragma unroll
      for (int ct = 0; ct < 8; ct++) {
        int c = ct * 16 + r;
        short8 bh = *(const short8*)&wthi[c * 72 + kk0 + q * 8];
        short8 bl = *(const short8*)&wtlo[c * 72 + kk0 + q * 8];
        acc[0][ct] = __builtin_amdgcn_mfma_f32_16x16x32_bf16(ahi0, bh, acc[0][ct], 0, 0, 0);
        acc[0][ct] = __builtin_amdgcn_mfma_f32_16x16x32_bf16(alo0, bh, acc[0][ct], 0, 0, 0);
        acc[0][ct] = __builtin_amdgcn_mfma_f32_16x16x32_bf16(ahi0, bl, acc[0][ct], 0, 0, 0);
        acc[1][ct] = __builtin_amdgcn_mfma_f32_16x16x32_bf16(ahi1, bh, acc[1][ct], 0, 0, 0);
        acc[1][ct] = __builtin_amdgcn_mfma_f32_16x16x32_bf16(alo1, bh, acc[1][ct], 0, 0, 0);
        acc[1][ct] = __builtin_amdgcn_mfma_f32_16x16x32_bf16(ahi1, bl, acc[1][ct], 0, 0, 0);
      }
    }
  }

  // epilogue: C/D layout col = lane&15, row = q*4 + reg
#pragma unroll
  for (int rt = 0; rt < 2; rt++) {
#pragma unroll
    for (int i = 0; i < 4; i++) {
      long row = rowbase + rt * 16 + q * 4 + i;
      if (row < n) {
#pragma unroll
        for (int ct = 0; ct < 8; ct++) {
          int col = ct * 16 + r;
          float v = acc[rt][ct][i];
          if (bias) v += bias[col];
          if (act == 1) v = elu1(v);
          if (omode == 0) {
            Yf[row * D + col] = v;
          } else {
            short hi = f2bf(v);
            short lo = f2bf(v - bf2f(hi));
            Ys[row * 256 + col] = hi;
            Ys[row * 256 + 128 + col] = lo;
          }
        }
      }
    }
  }
}

// ---------------- aggregation ----------------
// Y[d] = relu(sum_{e: dst=d} T[src]*norm + T[d]*dis[d]^2 + b)
// one wave per node, float2 per lane, unroll x8 (8 gathers in flight).
// Output: split bf16 hi/lo planes (row*256); optionally fp32 too (emb).

__global__ __launch_bounds__(256) void k_agg(const float* __restrict__ T,
                                             const int* __restrict__ rowptr,
                                             const int* __restrict__ counts,
                                             const int2* __restrict__ cpack,
                                             const float* __restrict__ dis,
                                             const float* __restrict__ bias,
                                             short* __restrict__ Ys,
                                             float* __restrict__ Yf, int n) {
  int node = blockIdx.x * 4 + (threadIdx.x >> 6);
  if (node >= n) return;
  int lane = threadIdx.x & 63;
  const float2* T2 = (const float2*)T;

  int s = rowptr[node];
  int e = s + counts[node];
  float dv = dis[node];
  float2 t = T2[(size_t)node * 64 + lane];
  float ax = t.x * (dv * dv), ay = t.y * (dv * dv);
  float bx2 = 0.f, by2 = 0.f, cx = 0.f, cy = 0.f, dx = 0.f, dy = 0.f;

  int j = s;
  for (; j + 7 < e; j += 8) {
    int2 m0 = cpack[j],     m1 = cpack[j + 1], m2 = cpack[j + 2], m3 = cpack[j + 3];
    int2 m4 = cpack[j + 4], m5 = cpack[j + 5], m6 = cpack[j + 6], m7 = cpack[j + 7];
    float2 v0 = T2[(size_t)m0.x * 64 + lane];
    float2 v1 = T2[(size_t)m1.x * 64 + lane];
    float2 v2 = T2[(size_t)m2.x * 64 + lane];
    float2 v3 = T2[(size_t)m3.x * 64 + lane];
    float2 v4 = T2[(size_t)m4.x * 64 + lane];
    float2 v5 = T2[(size_t)m5.x * 64 + lane];
    float2 v6 = T2[(size_t)m6.x * 64 + lane];
    float2 v7 = T2[(size_t)m7.x * 64 + lane];
    float n0 = __int_as_float(m0.y), n1 = __int_as_float(m1.y);
    float n2 = __int_as_float(m2.y), n3 = __int_as_float(m3.y);
    float n4 = __int_as_float(m4.y), n5 = __int_as_float(m5.y);
    float n6 = __int_as_float(m6.y), n7 = __int_as_float(m7.y);
    ax  += v0.x * n0; ay  += v0.y * n0;
    bx2 += v1.x * n1; by2 += v1.y * n1;
    cx  += v2.x * n2; cy  += v2.y * n2;
    dx  += v3.x * n3; dy  += v3.y * n3;
    ax  += v4.x * n4; ay  += v4.y * n4;
    bx2 += v5.x * n5; by2 += v5.y * n5;
    cx  += v6.x * n6; cy  += v6.y * n6;
    dx  += v7.x * n7; dy  += v7.y * n7;
  }
  for (; j + 3 < e; j += 4) {
    int2 m0 = cpack[j], m1 = cpack[j + 1], m2 = cpack[j + 2], m3 = cpack[j + 3];
    float2 v0 = T2[(size_t)m0.x * 64 + lane];
    float2 v1 = T2[(size_t)m1.x * 64 + lane];
    float2 v2 = T2[(size_t)m2.x * 64 + lane];
    float2 v3 = T2[(size_t)m3.x * 64 + lane];
    float n0 = __int_as_float(m0.y), n1 = __int_as_float(m1.y);
    float n2 = __int_as_float(m2.y), n3 = __int_as_float(m3.y);
    ax  += v0.x * n0; ay  += v0.y * n0;
    bx2 += v1.x * n1; by2 += v1.y * n1;
    cx  += v2.x * n2; cy  += v2.y * n2;
    dx  += v3.x * n3; dy  += v3.y * n3;
  }
  for (; j < e; ++j) {
    int2 m0 = cpack[j];
    float2 v0 = T2[(size_t)m0.x * 64 + lane];
    float n0 = __int_as_float(m0.y);
    ax += v0.x * n0; ay += v0.y * n0;
  }

  const float2* b2p = (const float2*)bias;
  float2 bb = b2p[lane];
  float ox = fmaxf((ax + bx2) + (cx + dx) + bb.x, 0.f);
  float oy = fmaxf((ay + by2) + (cy + dy) + bb.y, 0.f);

  // split bf16 output planes
  short h0 = f2bf(ox);
  short l0 = f2bf(ox - bf2f(h0));
  short h1 = f2bf(oy);
  short l1 = f2bf(oy - bf2f(h1));
  *(short2*)&Ys[(size_t)node * 256 + lane * 2] = make_short2(h0, h1);
  *(short2*)&Ys[(size_t)node * 256 + 128 + lane * 2] = make_short2(l0, l1);
  if (Yf) {
    float2 o; o.x = ox; o.y = oy;
    *(float2*)&Yf[(size_t)node * D + lane * 2] = o;
  }
}

// ---------------- MLP head: MFMA GEMM (128->48 cols, 40 valid) + fused softmax ----
// A pre-split (row*256 hi/lo planes).

__global__ __launch_bounds__(256) void k_head(const short* __restrict__ Ms,
                                              const short* __restrict__ Whi,
                                              const short* __restrict__ Wlo,
                                              const float* __restrict__ b,
                                              float* __restrict__ logits,
                                              float* __restrict__ probs, int n) {
  int tid = threadIdx.x;
  int wave = tid >> 6, lane = tid & 63;
  int q = lane >> 4, r = lane & 15;

  long rowbase = (long)blockIdx.x * 128 + wave * 32;
  long row0 = rowbase + r;
  long row1 = rowbase + 16 + r;
  long rc0 = row0 < n ? row0 : (n - 1);
  long rc1 = row1 < n ? row1 : (n - 1);

  floatx4 acc[2][3];
#pragma unroll
  for (int rt = 0; rt < 2; rt++)
#pragma unroll
    for (int ct = 0; ct < 3; ct++) acc[rt][ct] = (floatx4){0.f, 0.f, 0.f, 0.f};

#pragma unroll
  for (int ks = 0; ks < 4; ks++) {
    const short* p0 = Ms + rc0 * 256 + ks * 32 + q * 8;
    const short* p1 = Ms + rc1 * 256 + ks * 32 + q * 8;
    short8 ahi0 = *(const short8*)p0;
    short8 alo0 = *(const short8*)(p0 + 128);
    short8 ahi1 = *(const short8*)p1;
    short8 alo1 = *(const short8*)(p1 + 128);
#pragma unroll
    for (int ct = 0; ct < 3; ct++) {
      int c = ct * 16 + r;
      short8 bh = *(const short8*)&Whi[c * D + ks * 32 + q * 8];
      short8 bl = *(const short8*)&Wlo[c * D + ks * 32 + q * 8];
      acc[0][ct] = __builtin_amdgcn_mfma_f32_16x16x32_bf16(ahi0, bh, acc[0][ct], 0, 0, 0);
      acc[0][ct] = __builtin_amdgcn_mfma_f32_16x16x32_bf16(alo0, bh, acc[0][ct], 0, 0, 0);
      acc[0][ct] = __builtin_amdgcn_mfma_f32_16x16x32_bf16(ahi0, bl, acc[0][ct], 0, 0, 0);
      acc[1][ct] = __builtin_amdgcn_mfma_f32_16x16x32_bf16(ahi1, bh, acc[1][ct], 0, 0, 0);
      acc[1][ct] = __builtin_amdgcn_mfma_f32_16x16x32_bf16(alo1, bh, acc[1][ct], 0, 0, 0);
      acc[1][ct] = __builtin_amdgcn_mfma_f32_16x16x32_bf16(ahi1, bl, acc[1][ct], 0, 0, 0);
    }
  }

  float bb0 = b[r];
  float bb1 = b[16 + r];
  float bb2 = (r < 8) ? b[32 + r] : 0.f;

#pragma unroll
  for (int rt = 0; rt < 2; rt++) {
#pragma unroll
    for (int i = 0; i < 4; i++) {
      long row = rowbase + rt * 16 + q * 4 + i;
      float v0 = acc[rt][0][i] + bb0;
      float v1 = acc[rt][1][i] + bb1;
      float v2 = (r < 8) ? (acc[rt][2][i] + bb2) : -INFINITY;
      float mx = fmaxf(fmaxf(v0, v1), v2);
      mx = fmaxf(mx, __shfl_xor(mx, 1));
      mx = fmaxf(mx, __shfl_xor(mx, 2));
      mx = fmaxf(mx, __shfl_xor(mx, 4));
      mx = fmaxf(mx, __shfl_xor(mx, 8));
      float e0 = expf(v0 - mx);
      float e1 = expf(v1 - mx);
      float e2 = (r < 8) ? expf(v2 - mx) : 0.f;
      float sm = e0 + e1 + e2;
      sm += __shfl_xor(sm, 1);
      sm += __shfl_xor(sm, 2);
      sm += __shfl_xor(sm, 4);
      sm += __shfl_xor(sm, 8);
      float inv = 1.f / sm;
      if (row < n) {
        float* lp = logits + row * 40;
        float* pp = probs + row * 40;
        lp[r] = v0;      pp[r] = e0 * inv;
        lp[16 + r] = v1; pp[16 + r] = e1 * inv;
        if (r < 8) { lp[32 + r] = v2; pp[32 + r] = e2 * inv; }
      }
    }
  }
}

// ---------------- launcher ----------------

extern "C" void kernel_launch(void* const* d_in, const int* in_sizes, int n_in,
                              void* d_out, int out_size, void* d_ws, size_t ws_size,
                              hipStream_t stream) {
  const float* x   = (const float*)d_in[0];
  const int*   ei  = (const int*)d_in[1];
  const float* W1  = (const float*)d_in[2];
  const float* b1  = (const float*)d_in[3];
  const float* W2  = (const float*)d_in[4];
  const float* b2  = (const float*)d_in[5];
  const float* W3  = (const float*)d_in[6];
  const float* b3  = (const float*)d_in[7];
  const float* Wm1 = (const float*)d_in[8];
  const float* bm1 = (const float*)d_in[9];
  const float* Wm2 = (const float*)d_in[10];
  const float* bm2 = (const float*)d_in[11];

  int N = in_sizes[0] / D;
  int E = in_sizes[1] / 2;
  const int* srcp = ei;
  const int* dstp = ei + E;

  char* w = (char*)d_ws;
  auto alloc = [&](size_t bytes) -> char* {
    char* p = w;
    w += (bytes + 255) & ~(size_t)255;
    return p;
  };
  int*   counts = (int*)alloc((size_t)N * 4);
  int*   rowptr = (int*)alloc((size_t)N * 4);
  int*   cursor = (int*)alloc((size_t)N * 4);
  float* dis    = (float*)alloc((size_t)N * 4);
  int*   bsum   = (int*)alloc(1024);
  short* wsplit = (short*)alloc(4 * 32768 * 2);   // 4 weights x (hi+lo 16384 shorts)
  short* w2hi   = (short*)alloc(6144 * 2);
  short* w2lo   = (short*)alloc(6144 * 2);
  int2*  cpack  = (int2*)alloc((size_t)E * 8);
  float* tmp    = (float*)alloc((size_t)N * D * 4);  // fp32 gemm out / split mlp out
  short* hsplit = (short*)alloc((size_t)N * 256 * 2); // agg split output planes

  float* logits = (float*)d_out;
  float* probs  = logits + (size_t)N * 40;
  float* emb    = probs + (size_t)N * 40;

  // weight pre-split
  k_prep<<<(65536 + 6144 + 255) / 256, 256, 0, stream>>>(W1, W2, W3, Wm1, Wm2,
                                                         wsplit, w2hi, w2lo);
  // CSR build
  k_zero<<<(N + 255) / 256, 256, 0, stream>>>(counts, N);
  k_hist<<<(E + 255) / 256, 256, 0, stream>>>(dstp, counts, E);
  int nb = (N + 1023) / 1024;
  k_scan1<<<nb, 256, 0, stream>>>(counts, rowptr, bsum, N);
  k_scan2<<<1, 256, 0, stream>>>(bsum, nb);
  k_finish<<<(N + 255) / 256, 256, 0, stream>>>(rowptr, cursor, dis, counts, bsum, N);
  k_fill<<<(E + 255) / 256, 256, 0, stream>>>(srcp, dstp, cursor, dis, cpack, E);

  int gblocks = (N + 127) / 128;
  int ablocks = (N + 3) / 4;
  const short* Whi1 = wsplit;
  const short* Wlo1 = wsplit + 16384;
  const short* Whi2 = wsplit + 32768;
  const short* Wlo2 = wsplit + 32768 + 16384;
  const short* Whi3 = wsplit + 2 * 32768;
  const short* Wlo3 = wsplit + 2 * 32768 + 16384;
  const short* Whm1 = wsplit + 3 * 32768;
  const short* Wlm1 = wsplit + 3 * 32768 + 16384;

  // layer 1 (fp32 A in-kernel split)
  k_gemm<<<gblocks, 256, 0, stream>>>(x, nullptr, Whi1, Wlo1, nullptr,
                                      tmp, nullptr, N, 0, 0, 0);
  k_agg<<<ablocks, 256, 0, stream>>>(tmp, rowptr, counts, cpack, dis, b1,
                                     hsplit, nullptr, N);
  // layer 2 (pre-split A)
  k_gemm<<<gblocks, 256, 0, stream>>>(nullptr, hsplit, Whi2, Wlo2, nullptr,
                                      tmp, nullptr, N, 0, 1, 0);
  k_agg<<<ablocks, 256, 0, stream>>>(tmp, rowptr, counts, cpack, dis, b2,
                                     hsplit, nullptr, N);
  // layer 3 -> emb (split + fp32)
  k_gemm<<<gblocks, 256, 0, stream>>>(nullptr, hsplit, Whi3, Wlo3, nullptr,
                                      tmp, nullptr, N, 0, 1, 0);
  k_agg<<<ablocks, 256, 0, stream>>>(tmp, rowptr, counts, cpack, dis, b3,
                                     hsplit, emb, N);
  // MLP hidden (pre-split A, ELU, split out into tmp)
  k_gemm<<<gblocks, 256, 0, stream>>>(nullptr, hsplit, Whm1, Wlm1, bm1,
                                      nullptr, (short*)tmp, N, 1, 1, 1);
  // head (pre-split A)
  k_head<<<gblocks, 256, 0, stream>>>((const short*)tmp, w2hi, w2lo, bm2,
                                      logits, probs, N);
}

// Round 6
// 660.956 us; speedup vs baseline: 1.3669x; 1.2688x over previous
//
#include <hip/hip_runtime.h>
#include <math.h>

#define D 128

typedef __attribute__((ext_vector_type(8))) short short8;
typedef __attribute__((ext_vector_type(4))) float floatx4;
typedef __attribute__((ext_vector_type(2))) _Float16 half2v;
typedef __attribute__((ext_vector_type(8))) _Float16 half8;

// ---------------- graph preprocessing ----------------

__global__ __launch_bounds__(256) void k_zero(int* __restrict__ p, int n) {
  int i = blockIdx.x * 256 + threadIdx.x;
  if (i < n) p[i] = 0;
}

__global__ __launch_bounds__(256) void k_hist(const int* __restrict__ dst,
                                              int* __restrict__ counts, int E) {
  int e = blockIdx.x * 256 + threadIdx.x;
  if (e < E) atomicAdd(&counts[dst[e]], 1);
}

__global__ __launch_bounds__(256) void k_scan1(const int* __restrict__ in,
                                               int* __restrict__ out,
                                               int* __restrict__ bsum, int n) {
  __shared__ int sd[256];
  int tid = threadIdx.x;
  int base = blockIdx.x * 1024 + tid * 4;
  int v0 = 0, v1 = 0, v2 = 0, v3 = 0;
  if (base + 3 < n) {
    int4 t = *(const int4*)(in + base);
    v0 = t.x; v1 = t.y; v2 = t.z; v3 = t.w;
  } else {
    if (base     < n) v0 = in[base];
    if (base + 1 < n) v1 = in[base + 1];
    if (base + 2 < n) v2 = in[base + 2];
    if (base + 3 < n) v3 = in[base + 3];
  }
  int s = v0 + v1 + v2 + v3;
  sd[tid] = s;
  __syncthreads();
  for (int off = 1; off < 256; off <<= 1) {
    int t = (tid >= off) ? sd[tid - off] : 0;
    __syncthreads();
    sd[tid] += t;
    __syncthreads();
  }
  int incl = sd[tid];
  int excl = incl - s;
  if (tid == 255) bsum[blockIdx.x] = incl;
  int r = excl;
  if (base     < n) out[base]     = r; r += v0;
  if (base + 1 < n) out[base + 1] = r; r += v1;
  if (base + 2 < n) out[base + 2] = r; r += v2;
  if (base + 3 < n) out[base + 3] = r;
}

__global__ __launch_bounds__(256) void k_scan2(int* __restrict__ bsum, int nb) {
  __shared__ int sd[256];
  int tid = threadIdx.x;
  int v = (tid < nb) ? bsum[tid] : 0;
  sd[tid] = v;
  __syncthreads();
  for (int off = 1; off < 256; off <<= 1) {
    int t = (tid >= off) ? sd[tid - off] : 0;
    __syncthreads();
    sd[tid] += t;
    __syncthreads();
  }
  int excl = sd[tid] - v;
  if (tid < nb) bsum[tid] = excl;
}

__global__ __launch_bounds__(256) void k_finish(int* __restrict__ rowptr,
                                                int* __restrict__ cursor,
                                                float* __restrict__ dis,
                                                const int* __restrict__ counts,
                                                const int* __restrict__ bsum, int n) {
  int i = blockIdx.x * 256 + threadIdx.x;
  if (i < n) {
    int r = rowptr[i] + bsum[i >> 10];
    rowptr[i] = r;
    cursor[i] = r;
    dis[i] = rsqrtf((float)(counts[i] + 1));
  }
}

// packed CSR payload: one 8B scatter per edge (src, norm-bits)
__global__ __launch_bounds__(256) void k_fill(const int* __restrict__ src,
                                              const int* __restrict__ dst,
                                              int* __restrict__ cursor,
                                              const float* __restrict__ dis,
                                              int2* __restrict__ cpack, int E) {
  int e = blockIdx.x * 256 + threadIdx.x;
  if (e < E) {
    int s = src[e], d = dst[e];
    int pos = atomicAdd(&cursor[d], 1);
    float nw = dis[s] * dis[d];
    cpack[pos] = make_int2(s, __float_as_int(nw));
  }
}

// ---------------- weight pre-split (once per call) ----------------
// 128x128 weights -> image [c][k]: hi/lo bf16 of W[k][c].
// Wm2 (128x40, padded 48 cols) -> image [c][k]: hi/lo of Wm2[k][c].

__device__ __forceinline__ short f2bf(float v) {
  unsigned u = __float_as_uint(v);
  unsigned r = (u + 0x7FFFu + ((u >> 16) & 1u)) >> 16;
  return (short)r;
}
__device__ __forceinline__ float bf2f(short s) {
  return __uint_as_float(((unsigned)(unsigned short)s) << 16);
}

__global__ __launch_bounds__(256) void k_prep(const float* __restrict__ W1,
                                              const float* __restrict__ W2,
                                              const float* __restrict__ W3,
                                              const float* __restrict__ Wm1,
                                              const float* __restrict__ Wm2,
                                              short* __restrict__ wsplit,
                                              short* __restrict__ w2hi,
                                              short* __restrict__ w2lo) {
  int idx = blockIdx.x * 256 + threadIdx.x;
  if (idx < 65536) {
    int w = idx >> 14;            // which weight
    int rem = idx & 16383;        // c*128 + k
    int c = rem >> 7, k = rem & 127;
    const float* Ws = (w == 0) ? W1 : (w == 1) ? W2 : (w == 2) ? W3 : Wm1;
    float v = Ws[k * D + c];
    short hi = f2bf(v);
    short lo = f2bf(v - bf2f(hi));
    wsplit[(size_t)w * 32768 + rem] = hi;
    wsplit[(size_t)w * 32768 + 16384 + rem] = lo;
  } else if (idx < 65536 + 6144) {
    int i2 = idx - 65536;         // c*128 + k, c in 0..47
    int c = i2 >> 7, k = i2 & 127;
    float v = (c < 40) ? Wm2[k * 40 + c] : 0.f;
    short hi = f2bf(v);
    short lo = f2bf(v - bf2f(hi));
    w2hi[i2] = hi;
    w2lo[i2] = lo;
  }
}

// ---------------- bf16-split MFMA GEMM: Y = X @ W (+bias, +ELU) ----------------
// B staged in LDS (padded stride 72, 16B-aligned rows) per half-K.
// A: amode=0 fp32 rows; amode=2 fp16 rows (exact hi/lo split in-kernel).
// 3-product reconstruction: hi*hi + lo*hi + hi*lo.
// Output: fp16 rows (256B).

__device__ __forceinline__ float elu1(float x) {
  return x > 0.f ? x : (expf(x) - 1.f);
}

__global__ __launch_bounds__(256, 2) void k_gemm(const float* __restrict__ Xf,
                                                 const _Float16* __restrict__ Xh,
                                                 const short* __restrict__ Whi,
                                                 const short* __restrict__ Wlo,
                                                 const float* __restrict__ bias,
                                                 _Float16* __restrict__ Yh,
                                                 int n, int act, int amode) {
  __shared__ short wthi[128 * 72];  // [c][kk-half], padded stride 72 (144B, 16B-aligned)
  __shared__ short wtlo[128 * 72];

  int tid = threadIdx.x;
  int wave = tid >> 6, lane = tid & 63;
  int q = lane >> 4, r = lane & 15;

  long rowbase = (long)blockIdx.x * 128 + wave * 32;
  long row0 = rowbase + r;
  long row1 = rowbase + 16 + r;
  long rc0 = row0 < n ? row0 : (n - 1);
  long rc1 = row1 < n ? row1 : (n - 1);

  floatx4 acc[2][8];
#pragma unroll
  for (int rt = 0; rt < 2; rt++)
#pragma unroll
    for (int ct = 0; ct < 8; ct++) acc[rt][ct] = (floatx4){0.f, 0.f, 0.f, 0.f};

  for (int h = 0; h < 2; h++) {
    __syncthreads();
    // stage half-K of pre-split W images into padded LDS
#pragma unroll
    for (int i = 0; i < 4; i++) {
      int cs = i * 256 + tid;           // 1024 chunks of 8 shorts
      int c = cs >> 3, o = (cs & 7) * 8;
      *(short8*)&wthi[c * 72 + o] = *(const short8*)&Whi[c * D + h * 64 + o];
      *(short8*)&wtlo[c * 72 + o] = *(const short8*)&Wlo[c * D + h * 64 + o];
    }
    __syncthreads();

#pragma unroll
    for (int ks2 = 0; ks2 < 2; ks2++) {
      int ksg = h * 2 + ks2;            // global k-step 0..3
      int kk0 = ks2 * 32;
      short8 ahi0, alo0, ahi1, alo1;
      if (amode == 2) {
        half8 a0 = *(const half8*)(Xh + rc0 * D + ksg * 32 + q * 8);
        half8 a1 = *(const half8*)(Xh + rc1 * D + ksg * 32 + q * 8);
#pragma unroll
        for (int j = 0; j < 8; j++) {
          float v = (float)a0[j];
          short hi = f2bf(v);
          ahi0[j] = hi; alo0[j] = f2bf(v - bf2f(hi));
          v = (float)a1[j];
          hi = f2bf(v);
          ahi1[j] = hi; alo1[j] = f2bf(v - bf2f(hi));
        }
      } else {
        const floatx4* x0 = (const floatx4*)(Xf + rc0 * D);
        const floatx4* x1 = (const floatx4*)(Xf + rc1 * D);
        int xi = ksg * 8 + q * 2;
        floatx4 a0 = x0[xi], a0b = x0[xi + 1];
        floatx4 a1 = x1[xi], a1b = x1[xi + 1];
#pragma unroll
        for (int j = 0; j < 4; j++) {
          float v = a0[j];  short hi = f2bf(v);
          ahi0[j] = hi; alo0[j] = f2bf(v - bf2f(hi));
          v = a0b[j]; hi = f2bf(v);
          ahi0[4 + j] = hi; alo0[4 + j] = f2bf(v - bf2f(hi));
          v = a1[j];  hi = f2bf(v);
          ahi1[j] = hi; alo1[j] = f2bf(v - bf2f(hi));
          v = a1b[j]; hi = f2bf(v);
          ahi1[4 + j] = hi; alo1[4 + j] = f2bf(v - bf2f(hi));
        }
      }
#pragma unroll
      for (int ct = 0; ct < 8; ct++) {
        int c = ct * 16 + r;
        short8 bh = *(const short8*)&wthi[c * 72 + kk0 + q * 8];
        short8 bl = *(const short8*)&wtlo[c * 72 + kk0 + q * 8];
        acc[0][ct] = __builtin_amdgcn_mfma_f32_16x16x32_bf16(ahi0, bh, acc[0][ct], 0, 0, 0);
        acc[0][ct] = __builtin_amdgcn_mfma_f32_16x16x32_bf16(alo0, bh, acc[0][ct], 0, 0, 0);
        acc[0][ct] = __builtin_amdgcn_mfma_f32_16x16x32_bf16(ahi0, bl, acc[0][ct], 0, 0, 0);
        acc[1][ct] = __builtin_amdgcn_mfma_f32_16x16x32_bf16(ahi1, bh, acc[1][ct], 0, 0, 0);
        acc[1][ct] = __builtin_amdgcn_mfma_f32_16x16x32_bf16(alo1, bh, acc[1][ct], 0, 0, 0);
        acc[1][ct] = __builtin_amdgcn_mfma_f32_16x16x32_bf16(ahi1, bl, acc[1][ct], 0, 0, 0);
      }
    }
  }

  // epilogue: C/D layout col = lane&15, row = q*4 + reg; fp16 out
#pragma unroll
  for (int rt = 0; rt < 2; rt++) {
#pragma unroll
    for (int i = 0; i < 4; i++) {
      long row = rowbase + rt * 16 + q * 4 + i;
      if (row < n) {
#pragma unroll
        for (int ct = 0; ct < 8; ct++) {
          int col = ct * 16 + r;
          float v = acc[rt][ct][i];
          if (bias) v += bias[col];
          if (act == 1) v = elu1(v);
          Yh[row * D + col] = (_Float16)v;
        }
      }
    }
  }
}

// ---------------- aggregation ----------------
// Y[d] = relu(sum_{e: dst=d} T[src]*norm + T[d]*dis[d]^2 + b)
// one wave per node; fp16 gather rows (256B), fp32 accumulate, unroll x8.
// Output: fp16 row; optionally fp32 too (emb, layer 3).

__global__ __launch_bounds__(256) void k_agg(const _Float16* __restrict__ T,
                                             const int* __restrict__ rowptr,
                                             const int* __restrict__ counts,
                                             const int2* __restrict__ cpack,
                                             const float* __restrict__ dis,
                                             const float* __restrict__ bias,
                                             _Float16* __restrict__ Yh,
                                             float* __restrict__ Yf, int n) {
  int node = blockIdx.x * 4 + (threadIdx.x >> 6);
  if (node >= n) return;
  int lane = threadIdx.x & 63;
  const half2v* T2 = (const half2v*)T;

  int s = rowptr[node];
  int e = s + counts[node];
  float dv = dis[node];
  half2v t = T2[(size_t)node * 64 + lane];
  float ax = (float)t[0] * (dv * dv), ay = (float)t[1] * (dv * dv);
  float bx2 = 0.f, by2 = 0.f, cx = 0.f, cy = 0.f, dx = 0.f, dy = 0.f;

  int j = s;
  for (; j + 7 < e; j += 8) {
    int2 m0 = cpack[j],     m1 = cpack[j + 1], m2 = cpack[j + 2], m3 = cpack[j + 3];
    int2 m4 = cpack[j + 4], m5 = cpack[j + 5], m6 = cpack[j + 6], m7 = cpack[j + 7];
    half2v v0 = T2[(size_t)m0.x * 64 + lane];
    half2v v1 = T2[(size_t)m1.x * 64 + lane];
    half2v v2 = T2[(size_t)m2.x * 64 + lane];
    half2v v3 = T2[(size_t)m3.x * 64 + lane];
    half2v v4 = T2[(size_t)m4.x * 64 + lane];
    half2v v5 = T2[(size_t)m5.x * 64 + lane];
    half2v v6 = T2[(size_t)m6.x * 64 + lane];
    half2v v7 = T2[(size_t)m7.x * 64 + lane];
    float n0 = __int_as_float(m0.y), n1 = __int_as_float(m1.y);
    float n2 = __int_as_float(m2.y), n3 = __int_as_float(m3.y);
    float n4 = __int_as_float(m4.y), n5 = __int_as_float(m5.y);
    float n6 = __int_as_float(m6.y), n7 = __int_as_float(m7.y);
    ax  += (float)v0[0] * n0; ay  += (float)v0[1] * n0;
    bx2 += (float)v1[0] * n1; by2 += (float)v1[1] * n1;
    cx  += (float)v2[0] * n2; cy  += (float)v2[1] * n2;
    dx  += (float)v3[0] * n3; dy  += (float)v3[1] * n3;
    ax  += (float)v4[0] * n4; ay  += (float)v4[1] * n4;
    bx2 += (float)v5[0] * n5; by2 += (float)v5[1] * n5;
    cx  += (float)v6[0] * n6; cy  += (float)v6[1] * n6;
    dx  += (float)v7[0] * n7; dy  += (float)v7[1] * n7;
  }
  for (; j + 3 < e; j += 4) {
    int2 m0 = cpack[j], m1 = cpack[j + 1], m2 = cpack[j + 2], m3 = cpack[j + 3];
    half2v v0 = T2[(size_t)m0.x * 64 + lane];
    half2v v1 = T2[(size_t)m1.x * 64 + lane];
    half2v v2 = T2[(size_t)m2.x * 64 + lane];
    half2v v3 = T2[(size_t)m3.x * 64 + lane];
    float n0 = __int_as_float(m0.y), n1 = __int_as_float(m1.y);
    float n2 = __int_as_float(m2.y), n3 = __int_as_float(m3.y);
    ax  += (float)v0[0] * n0; ay  += (float)v0[1] * n0;
    bx2 += (float)v1[0] * n1; by2 += (float)v1[1] * n1;
    cx  += (float)v2[0] * n2; cy  += (float)v2[1] * n2;
    dx  += (float)v3[0] * n3; dy  += (float)v3[1] * n3;
  }
  for (; j < e; ++j) {
    int2 m0 = cpack[j];
    half2v v0 = T2[(size_t)m0.x * 64 + lane];
    float n0 = __int_as_float(m0.y);
    ax += (float)v0[0] * n0; ay += (float)v0[1] * n0;
  }

  const float2* b2p = (const float2*)bias;
  float2 bb = b2p[lane];
  float ox = fmaxf((ax + bx2) + (cx + dx) + bb.x, 0.f);
  float oy = fmaxf((ay + by2) + (cy + dy) + bb.y, 0.f);

  half2v oh;
  oh[0] = (_Float16)ox;
  oh[1] = (_Float16)oy;
  *(half2v*)&Yh[(size_t)node * D + lane * 2] = oh;
  if (Yf) {
    float2 o; o.x = ox; o.y = oy;
    *(float2*)&Yf[(size_t)node * D + lane * 2] = o;
  }
}

// ---------------- MLP head: MFMA GEMM (128->48 cols, 40 valid) + fused softmax ----
// A: fp16 rows (exact hi/lo split in-kernel). B direct from global (L2-hot).

__global__ __launch_bounds__(256) void k_head(const _Float16* __restrict__ M,
                                              const short* __restrict__ Whi,
                                              const short* __restrict__ Wlo,
                                              const float* __restrict__ b,
                                              float* __restrict__ logits,
                                              float* __restrict__ probs, int n) {
  int tid = threadIdx.x;
  int wave = tid >> 6, lane = tid & 63;
  int q = lane >> 4, r = lane & 15;

  long rowbase = (long)blockIdx.x * 128 + wave * 32;
  long row0 = rowbase + r;
  long row1 = rowbase + 16 + r;
  long rc0 = row0 < n ? row0 : (n - 1);
  long rc1 = row1 < n ? row1 : (n - 1);

  floatx4 acc[2][3];
#pragma unroll
  for (int rt = 0; rt < 2; rt++)
#pragma unroll
    for (int ct = 0; ct < 3; ct++) acc[rt][ct] = (floatx4){0.f, 0.f, 0.f, 0.f};

#pragma unroll
  for (int ks = 0; ks < 4; ks++) {
    half8 a0 = *(const half8*)(M + rc0 * D + ks * 32 + q * 8);
    half8 a1 = *(const half8*)(M + rc1 * D + ks * 32 + q * 8);
    short8 ahi0, alo0, ahi1, alo1;
#pragma unroll
    for (int j = 0; j < 8; j++) {
      float v = (float)a0[j];
      short hi = f2bf(v);
      ahi0[j] = hi; alo0[j] = f2bf(v - bf2f(hi));
      v = (float)a1[j];
      hi = f2bf(v);
      ahi1[j] = hi; alo1[j] = f2bf(v - bf2f(hi));
    }
#pragma unroll
    for (int ct = 0; ct < 3; ct++) {
      int c = ct * 16 + r;
      short8 bh = *(const short8*)&Whi[c * D + ks * 32 + q * 8];
      short8 bl = *(const short8*)&Wlo[c * D + ks * 32 + q * 8];
      acc[0][ct] = __builtin_amdgcn_mfma_f32_16x16x32_bf16(ahi0, bh, acc[0][ct], 0, 0, 0);
      acc[0][ct] = __builtin_amdgcn_mfma_f32_16x16x32_bf16(alo0, bh, acc[0][ct], 0, 0, 0);
      acc[0][ct] = __builtin_amdgcn_mfma_f32_16x16x32_bf16(ahi0, bl, acc[0][ct], 0, 0, 0);
      acc[1][ct] = __builtin_amdgcn_mfma_f32_16x16x32_bf16(ahi1, bh, acc[1][ct], 0, 0, 0);
      acc[1][ct] = __builtin_amdgcn_mfma_f32_16x16x32_bf16(alo1, bh, acc[1][ct], 0, 0, 0);
      acc[1][ct] = __builtin_amdgcn_mfma_f32_16x16x32_bf16(ahi1, bl, acc[1][ct], 0, 0, 0);
    }
  }

  float bb0 = b[r];
  float bb1 = b[16 + r];
  float bb2 = (r < 8) ? b[32 + r] : 0.f;

#pragma unroll
  for (int rt = 0; rt < 2; rt++) {
#pragma unroll
    for (int i = 0; i < 4; i++) {
      long row = rowbase + rt * 16 + q * 4 + i;
      float v0 = acc[rt][0][i] + bb0;
      float v1 = acc[rt][1][i] + bb1;
      float v2 = (r < 8) ? (acc[rt][2][i] + bb2) : -INFINITY;
      float mx = fmaxf(fmaxf(v0, v1), v2);
      mx = fmaxf(mx, __shfl_xor(mx, 1));
      mx = fmaxf(mx, __shfl_xor(mx, 2));
      mx = fmaxf(mx, __shfl_xor(mx, 4));
      mx = fmaxf(mx, __shfl_xor(mx, 8));
      float e0 = expf(v0 - mx);
      float e1 = expf(v1 - mx);
      float e2 = (r < 8) ? expf(v2 - mx) : 0.f;
      float sm = e0 + e1 + e2;
      sm += __shfl_xor(sm, 1);
      sm += __shfl_xor(sm, 2);
      sm += __shfl_xor(sm, 4);
      sm += __shfl_xor(sm, 8);
      float inv = 1.f / sm;
      if (row < n) {
        float* lp = logits + row * 40;
        float* pp = probs + row * 40;
        lp[r] = v0;      pp[r] = e0 * inv;
        lp[16 + r] = v1; pp[16 + r] = e1 * inv;
        if (r < 8) { lp[32 + r] = v2; pp[32 + r] = e2 * inv; }
      }
    }
  }
}

// ---------------- launcher ----------------

extern "C" void kernel_launch(void* const* d_in, const int* in_sizes, int n_in,
                              void* d_out, int out_size, void* d_ws, size_t ws_size,
                              hipStream_t stream) {
  const float* x   = (const float*)d_in[0];
  const int*   ei  = (const int*)d_in[1];
  const float* W1  = (const float*)d_in[2];
  const float* b1  = (const float*)d_in[3];
  const float* W2  = (const float*)d_in[4];
  const float* b2  = (const float*)d_in[5];
  const float* W3  = (const float*)d_in[6];
  const float* b3  = (const float*)d_in[7];
  const float* Wm1 = (const float*)d_in[8];
  const float* bm1 = (const float*)d_in[9];
  const float* Wm2 = (const float*)d_in[10];
  const float* bm2 = (const float*)d_in[11];

  int N = in_sizes[0] / D;
  int E = in_sizes[1] / 2;
  const int* srcp = ei;
  const int* dstp = ei + E;

  char* w = (char*)d_ws;
  auto alloc = [&](size_t bytes) -> char* {
    char* p = w;
    w += (bytes + 255) & ~(size_t)255;
    return p;
  };
  int*   counts = (int*)alloc((size_t)N * 4);
  int*   rowptr = (int*)alloc((size_t)N * 4);
  int*   cursor = (int*)alloc((size_t)N * 4);
  float* dis    = (float*)alloc((size_t)N * 4);
  int*   bsum   = (int*)alloc(1024);
  short* wsplit = (short*)alloc(4 * 32768 * 2);   // 4 weights x (hi+lo 16384 shorts)
  short* w2hi   = (short*)alloc(6144 * 2);
  short* w2lo   = (short*)alloc(6144 * 2);
  int2*  cpack  = (int2*)alloc((size_t)E * 8);
  _Float16* tmp_h  = (_Float16*)alloc((size_t)N * D * 2);
  _Float16* hbuf_h = (_Float16*)alloc((size_t)N * D * 2);

  float* logits = (float*)d_out;
  float* probs  = logits + (size_t)N * 40;
  float* emb    = probs + (size_t)N * 40;

  // weight pre-split
  k_prep<<<(65536 + 6144 + 255) / 256, 256, 0, stream>>>(W1, W2, W3, Wm1, Wm2,
                                                         wsplit, w2hi, w2lo);
  // CSR build
  k_zero<<<(N + 255) / 256, 256, 0, stream>>>(counts, N);
  k_hist<<<(E + 255) / 256, 256, 0, stream>>>(dstp, counts, E);
  int nb = (N + 1023) / 1024;
  k_scan1<<<nb, 256, 0, stream>>>(counts, rowptr, bsum, N);
  k_scan2<<<1, 256, 0, stream>>>(bsum, nb);
  k_finish<<<(N + 255) / 256, 256, 0, stream>>>(rowptr, cursor, dis, counts, bsum, N);
  k_fill<<<(E + 255) / 256, 256, 0, stream>>>(srcp, dstp, cursor, dis, cpack, E);

  int gblocks = (N + 127) / 128;
  int ablocks = (N + 3) / 4;
  const short* Whi1 = wsplit;
  const short* Wlo1 = wsplit + 16384;
  const short* Whi2 = wsplit + 32768;
  const short* Wlo2 = wsplit + 32768 + 16384;
  const short* Whi3 = wsplit + 2 * 32768;
  const short* Wlo3 = wsplit + 2 * 32768 + 16384;
  const short* Whm1 = wsplit + 3 * 32768;
  const short* Wlm1 = wsplit + 3 * 32768 + 16384;

  // layer 1 (fp32 A)
  k_gemm<<<gblocks, 256, 0, stream>>>(x, nullptr, Whi1, Wlo1, nullptr,
                                      tmp_h, N, 0, 0);
  k_agg<<<ablocks, 256, 0, stream>>>(tmp_h, rowptr, counts, cpack, dis, b1,
                                     hbuf_h, nullptr, N);
  // layer 2 (fp16 A)
  k_gemm<<<gblocks, 256, 0, stream>>>(nullptr, hbuf_h, Whi2, Wlo2, nullptr,
                                      tmp_h, N, 0, 2);
  k_agg<<<ablocks, 256, 0, stream>>>(tmp_h, rowptr, counts, cpack, dis, b2,
                                     hbuf_h, nullptr, N);
  // layer 3 -> emb (fp16 + fp32)
  k_gemm<<<gblocks, 256, 0, stream>>>(nullptr, hbuf_h, Whi3, Wlo3, nullptr,
                                      tmp_h, N, 0, 2);
  k_agg<<<ablocks, 256, 0, stream>>>(tmp_h, rowptr, counts, cpack, dis, b3,
                                     hbuf_h, emb, N);
  // MLP hidden (fp16 A, ELU, fp16 out)
  k_gemm<<<gblocks, 256, 0, stream>>>(nullptr, hbuf_h, Whm1, Wlm1, bm1,
                                      tmp_h, N, 1, 2);
  // head (fp16 A)
  k_head<<<gblocks, 256, 0, stream>>>(tmp_h, w2hi, w2lo, bm2,
                                      logits, probs, N);
}